// Round 7
// baseline (600.649 us; speedup 1.0000x reference)
//
#include <hip/hip_runtime.h>

// out[B=1024, O=8192] = x[B, I=16384] @ (W*mask)[O, I]^T + bias[O]
// Phase 1: W*mask -> bf16 (ws), x -> bf16 (ws), nontemporal streaming.
// Phase 2: 256x256 bf16 MFMA GEMM, split-K=2, grid 256 (1 block/CU),
//          m201-style 4-phase/K-tile schedule: per phase {ds_read quad,
//          stage 1 half-tile, barrier, lgkmcnt(0), 16 MFMA, barrier},
//          counted vmcnt(4) once per K-tile, XOR-swizzled LDS (0 conflicts).
// Phase 3: reduce partials + bias.

#define IN_DIM 16384
#define OUT_DIM 8192
#define BATCH 1024

#define BM 256
#define BN 256
#define BK 64
#define KSPLIT 2
#define K_HALF (IN_DIM / KSPLIT)  // 8192
#define NT_K (K_HALF / BK)        // 128
#define NT256 (OUT_DIM / BN)      // 32
#define MT256 (BATCH / BM)        // 4

typedef __attribute__((ext_vector_type(8))) short bf16x8;
typedef __attribute__((ext_vector_type(4))) float f32x4;
typedef __attribute__((ext_vector_type(8))) unsigned short u16x8;

__device__ __forceinline__ unsigned short f2bf(float f) {
  unsigned int u = __float_as_uint(f);
  return (unsigned short)((u + 0x7fffu + ((u >> 16) & 1u)) >> 16);
}

#define GL16(g, l)                                                \
  __builtin_amdgcn_global_load_lds(                               \
      (const __attribute__((address_space(1))) void*)(g),         \
      (__attribute__((address_space(3))) void*)(l), 16, 0, 0)

__global__ __launch_bounds__(256) void prep_w_kernel(
    const f32x4* __restrict__ w, const f32x4* __restrict__ m,
    u16x8* __restrict__ out, int n8) {
  int i = blockIdx.x * blockDim.x + threadIdx.x;
  int stride = gridDim.x * blockDim.x;
  for (; i < n8; i += stride) {
    f32x4 w0 = __builtin_nontemporal_load(&w[2 * i]);
    f32x4 w1 = __builtin_nontemporal_load(&w[2 * i + 1]);
    f32x4 m0 = __builtin_nontemporal_load(&m[2 * i]);
    f32x4 m1 = __builtin_nontemporal_load(&m[2 * i + 1]);
    u16x8 o;
    o[0] = f2bf(w0[0] * m0[0]);
    o[1] = f2bf(w0[1] * m0[1]);
    o[2] = f2bf(w0[2] * m0[2]);
    o[3] = f2bf(w0[3] * m0[3]);
    o[4] = f2bf(w1[0] * m1[0]);
    o[5] = f2bf(w1[1] * m1[1]);
    o[6] = f2bf(w1[2] * m1[2]);
    o[7] = f2bf(w1[3] * m1[3]);
    __builtin_nontemporal_store(o, &out[i]);
  }
}

__global__ __launch_bounds__(256) void prep_x_kernel(
    const f32x4* __restrict__ x, u16x8* __restrict__ out, int n8) {
  int i = blockIdx.x * blockDim.x + threadIdx.x;
  int stride = gridDim.x * blockDim.x;
  for (; i < n8; i += stride) {
    f32x4 v0 = __builtin_nontemporal_load(&x[2 * i]);
    f32x4 v1 = __builtin_nontemporal_load(&x[2 * i + 1]);
    u16x8 o;
    o[0] = f2bf(v0[0]);
    o[1] = f2bf(v0[1]);
    o[2] = f2bf(v0[2]);
    o[3] = f2bf(v0[3]);
    o[4] = f2bf(v1[0]);
    o[5] = f2bf(v1[1]);
    o[6] = f2bf(v1[2]);
    o[7] = f2bf(v1[3]);
    __builtin_nontemporal_store(o, &out[i]);
  }
}

__global__ __launch_bounds__(256) void reduce_kernel(
    const f32x4* __restrict__ p0, const f32x4* __restrict__ p1,
    const f32x4* __restrict__ bias4, f32x4* __restrict__ out, int n4) {
  int i = blockIdx.x * blockDim.x + threadIdx.x;
  int stride = gridDim.x * blockDim.x;
  for (; i < n4; i += stride) {
    f32x4 a = p0[i];
    f32x4 b = p1[i];
    f32x4 c = bias4[i & (OUT_DIM / 4 - 1)];
    out[i] = a + b + c;
  }
}

// 256x256 tile, 8 waves (2M x 4N), per-wave 128x64, split-K=2.
// bid = (mt*2+kh)*32 + nt -> all sharers of N-panel nt on one XCD.
// LDS [slot][half][128][64] shorts per matrix (2 slots dbuf, 2 halves).
// Schedule per K-tile T (slot s=T&1, o=s^1), phases q=0..3:
//   q0: ds_read bF[4][2] + aF quad0; stage A0,A1(T+1)->o  (+4 loads)
//   q1: ds_read aF quad1;           stage B0(T+2)->s      (+2)
//   q2: ds_read aF quad2;           stage B1(T+2)->s      (+2)
//   q3: ds_read aF quad3;           vmcnt(4)  [certifies all of T+1]
//   each phase: barrier; lgkmcnt(0); setprio(1); 16 MFMA; setprio(0); barrier
// Safety: B regions of slot s are register-resident after q0's lgkmcnt(0)+
// end barrier -> q1/q2 overwrite OK; A regions of o last read at T-1 q3,
// drained before its end barrier -> q0 overwrite OK. vmcnt(4) leaves only
// B(T+2) (4 loads) in flight across the K-tile boundary (never drains).
__global__ __launch_bounds__(512, 2) void gemm256(
    const short* __restrict__ Ab, const short* __restrict__ Bb,
    float* __restrict__ out0, float* __restrict__ out1) {
  __shared__ short As[2][2][128 * 64];  // 64 KB
  __shared__ short Bs[2][2][128 * 64];  // 64 KB

  const int tid = threadIdx.x;
  const int lane = tid & 63;
  const int wv = tid >> 6;  // 0..7
  const int wr = wv >> 2;   // 0..1
  const int wc = wv & 3;    // 0..3
  const int fr = lane & 15;
  const int fq = lane >> 4;  // 0..3
  const int wv8 = wv * 8;

  const int bid = blockIdx.x;
  const int nt = bid & (NT256 - 1);
  const int rest = bid >> 5;  // mt*2 + kh
  const int mt = rest >> 1;
  const int kh = rest & 1;
  const int row0 = mt * BM;
  const int col0 = nt * BN;
  const int kbase = kh * K_HALF;
  float* __restrict__ dst = kh ? out1 : out0;

  // Staging: per GL16 issue, 512 threads cover 64 rows x 64 cols (8 KB).
  // thread -> row tid>>3, 16B chunk (tid&7); source chunk XOR-swizzled by
  // row&7 so LDS dest stays linear (rule 21: swizzle source + read, not dest).
  const int swz8 = ((tid & 7) ^ ((tid >> 3) & 7)) * 8;  // elements
  const short* srcA = Ab + (size_t)(row0 + (tid >> 3)) * IN_DIM + kbase + swz8;
  const short* srcB = Bb + (size_t)(col0 + (tid >> 3)) * IN_DIM + kbase + swz8;
  char* ldsA = (char*)As;
  char* ldsB = (char*)Bs;
  const int stg = wv8 * 128;  // wave-uniform LDS row offset within an issue

#define STAGE_A(h, kt, s)                                                  \
  do {                                                                     \
    GL16(srcA + (size_t)((h)*128) * IN_DIM + (size_t)(kt)*BK,              \
         ldsA + (s)*32768 + (h)*16384 + stg);                              \
    GL16(srcA + (size_t)((h)*128 + 64) * IN_DIM + (size_t)(kt)*BK,         \
         ldsA + (s)*32768 + (h)*16384 + 8192 + stg);                       \
  } while (0)
#define STAGE_B(h, kt, s)                                                  \
  do {                                                                     \
    GL16(srcB + (size_t)((h)*128) * IN_DIM + (size_t)(kt)*BK,              \
         ldsB + (s)*32768 + (h)*16384 + stg);                              \
    GL16(srcB + (size_t)((h)*128 + 64) * IN_DIM + (size_t)(kt)*BK,         \
         ldsB + (s)*32768 + (h)*16384 + 8192 + stg);                       \
  } while (0)

  // ds_read: frag at (tile row R, kchunk cg=ks*4+fq), half h=R>>7, r=R&127:
  // byte = slot*32768 + h*16384 + r*128 + ((cg ^ (r&7))*16); r&7 == fr&7.
  const int swzslot = (fq ^ (fr & 7)) * 16;
  const int Abase = wr * 16384 + fr * 128 + swzslot;
  const int Bbase = (wc >> 1) * 16384 + (wc & 1) * 8192 + fr * 128 + swzslot;

  f32x4 acc[8][4];
#pragma unroll
  for (int i = 0; i < 8; ++i)
#pragma unroll
    for (int j = 0; j < 4; ++j) acc[i][j] = (f32x4)0.f;

  // Prologue: T0 fully into slot 0, B(T1) into slot 1; vmcnt(4) certifies T0,
  // leaves B(T1) (4 loads) in flight.
  STAGE_A(0, 0, 0);
  STAGE_A(1, 0, 0);
  STAGE_B(0, 0, 0);
  STAGE_B(1, 0, 0);
  STAGE_B(0, 1, 1);
  STAGE_B(1, 1, 1);
  asm volatile("s_waitcnt vmcnt(4)" ::: "memory");
  __builtin_amdgcn_s_barrier();

  for (int t = 0; t < NT_K; ++t) {
    const int s = t & 1;
    const int o = s ^ 1;
    const char* tA = (const char*)As + s * 32768;
    const char* tB = (const char*)Bs + s * 32768;
    bf16x8 bF[4][2];
#pragma unroll
    for (int q = 0; q < 4; ++q) {
      bf16x8 aF[2][2];
      if (q == 0) {
#pragma unroll
        for (int n = 0; n < 4; ++n)
#pragma unroll
          for (int ks = 0; ks < 2; ++ks)
            bF[n][ks] =
                *(const bf16x8*)(tB + ((Bbase + n * 2048) ^ (ks << 6)));
      }
#pragma unroll
      for (int mi = 0; mi < 2; ++mi)
#pragma unroll
        for (int ks = 0; ks < 2; ++ks)
          aF[mi][ks] = *(const bf16x8*)(tA + ((Abase + (q * 2 + mi) * 2048) ^
                                              (ks << 6)));
      if (q == 0) {
        if (t + 1 < NT_K) {
          STAGE_A(0, t + 1, o);
          STAGE_A(1, t + 1, o);
        }
      } else if (q == 1) {
        if (t + 2 < NT_K) STAGE_B(0, t + 2, s);
      } else if (q == 2) {
        if (t + 2 < NT_K) STAGE_B(1, t + 2, s);
      } else {
        if (t < NT_K - 2)
          asm volatile("s_waitcnt vmcnt(4)" ::: "memory");
        else
          asm volatile("s_waitcnt vmcnt(0)" ::: "memory");
      }
      __builtin_amdgcn_s_barrier();
      asm volatile("s_waitcnt lgkmcnt(0)" ::: "memory");
      __builtin_amdgcn_sched_barrier(0);
      __builtin_amdgcn_s_setprio(1);
#pragma unroll
      for (int ks = 0; ks < 2; ++ks)
#pragma unroll
        for (int mi = 0; mi < 2; ++mi)
#pragma unroll
          for (int n = 0; n < 4; ++n)
            acc[q * 2 + mi][n] = __builtin_amdgcn_mfma_f32_16x16x32_bf16(
                aF[mi][ks], bF[n][ks], acc[q * 2 + mi][n], 0, 0, 0);
      __builtin_amdgcn_s_setprio(0);
      __builtin_amdgcn_s_barrier();
    }
  }

  // C/D layout: col = lane&15, row = (lane>>4)*4 + reg
#pragma unroll
  for (int m = 0; m < 8; ++m) {
#pragma unroll
    for (int n = 0; n < 4; ++n) {
      const int c = col0 + wc * 64 + n * 16 + fr;
      const int rb = row0 + wr * 128 + m * 16 + fq * 4;
#pragma unroll
      for (int tt = 0; tt < 4; ++tt)
        dst[(size_t)(rb + tt) * OUT_DIM + c] = acc[m][n][tt];
    }
  }
#undef STAGE_A
#undef STAGE_B
}

// Fallback (ws too small): fused f32->bf16 128x128 kernel, verified round 1.
__global__ __launch_bounds__(256) void gemm128_fused(
    const float* __restrict__ X, const float* __restrict__ W,
    const float* __restrict__ Msk, const float* __restrict__ bias,
    float* __restrict__ out) {
  __shared__ short As[128 * BK];
  __shared__ short Bs[128 * BK];
  const int tid = threadIdx.x;
  const int lane = tid & 63;
  const int wv4 = tid >> 6;
  const int wm = wv4 >> 1;
  const int wn = wv4 & 1;
  const int fr = lane & 15;
  const int fq = lane >> 4;
  const int bid = blockIdx.x;
  const int nt = bid & 63;
  const int mt = bid >> 6;
  const int row0 = mt * 128;
  const int col0 = nt * 128;
  f32x4 acc[4][4];
#pragma unroll
  for (int i = 0; i < 4; ++i)
#pragma unroll
    for (int j = 0; j < 4; ++j) acc[i][j] = (f32x4)0.f;
  for (int kt = 0; kt < IN_DIM / BK; ++kt) {
    const int k0 = kt * BK;
    __syncthreads();
#pragma unroll
    for (int is = 0; is < 4; ++is) {
      const int e = (is * 256 + tid) * 8;
      const int r = e >> 6;
      const int kk = e & 63;
      {
        const float* src = X + (size_t)(row0 + r) * IN_DIM + k0 + kk;
        f32x4 a0 = *(const f32x4*)src;
        f32x4 a1 = *(const f32x4*)(src + 4);
        bf16x8 v;
        v[0] = (short)f2bf(a0[0]); v[1] = (short)f2bf(a0[1]);
        v[2] = (short)f2bf(a0[2]); v[3] = (short)f2bf(a0[3]);
        v[4] = (short)f2bf(a1[0]); v[5] = (short)f2bf(a1[1]);
        v[6] = (short)f2bf(a1[2]); v[7] = (short)f2bf(a1[3]);
        *(bf16x8*)&As[r * BK + kk] = v;
      }
      {
        const float* sw = W + (size_t)(col0 + r) * IN_DIM + k0 + kk;
        const float* sm = Msk + (size_t)(col0 + r) * IN_DIM + k0 + kk;
        f32x4 w0 = *(const f32x4*)sw;
        f32x4 w1 = *(const f32x4*)(sw + 4);
        f32x4 m0 = *(const f32x4*)sm;
        f32x4 m1 = *(const f32x4*)(sm + 4);
        bf16x8 v;
        v[0] = (short)f2bf(w0[0] * m0[0]); v[1] = (short)f2bf(w0[1] * m0[1]);
        v[2] = (short)f2bf(w0[2] * m0[2]); v[3] = (short)f2bf(w0[3] * m0[3]);
        v[4] = (short)f2bf(w1[0] * m1[0]); v[5] = (short)f2bf(w1[1] * m1[1]);
        v[6] = (short)f2bf(w1[2] * m1[2]); v[7] = (short)f2bf(w1[3] * m1[3]);
        *(bf16x8*)&Bs[r * BK + kk] = v;
      }
    }
    __syncthreads();
#pragma unroll
    for (int ks = 0; ks < 2; ++ks) {
      bf16x8 af[4], bf[4];
#pragma unroll
      for (int i = 0; i < 4; ++i)
        af[i] = *(const bf16x8*)&As[(wm * 64 + i * 16 + fr) * BK + ks * 32 + fq * 8];
#pragma unroll
      for (int j = 0; j < 4; ++j)
        bf[j] = *(const bf16x8*)&Bs[(wn * 64 + j * 16 + fr) * BK + ks * 32 + fq * 8];
#pragma unroll
      for (int i = 0; i < 4; ++i)
#pragma unroll
        for (int j = 0; j < 4; ++j)
          acc[i][j] = __builtin_amdgcn_mfma_f32_16x16x32_bf16(af[i], bf[j],
                                                              acc[i][j], 0, 0, 0);
    }
  }
#pragma unroll
  for (int j = 0; j < 4; ++j) {
    const int c = col0 + wn * 64 + j * 16 + fr;
    const float bv = bias[c];
#pragma unroll
    for (int i = 0; i < 4; ++i) {
      const int rb = row0 + wm * 64 + i * 16 + fq * 4;
#pragma unroll
      for (int tt = 0; tt < 4; ++tt)
        out[(size_t)(rb + tt) * OUT_DIM + c] = acc[i][j][tt] + bv;
    }
  }
}

extern "C" void kernel_launch(void* const* d_in, const int* in_sizes, int n_in,
                              void* d_out, int out_size, void* d_ws, size_t ws_size,
                              hipStream_t stream) {
  const float* x = (const float*)d_in[0];
  const float* w = (const float*)d_in[1];
  const float* bias = (const float*)d_in[2];
  const float* mask = (const float*)d_in[3];
  float* out = (float*)d_out;

  const size_t wm_elems = (size_t)OUT_DIM * IN_DIM;
  const size_t xb_elems = (size_t)BATCH * IN_DIM;
  const size_t out_elems = (size_t)BATCH * OUT_DIM;
  const size_t need_bf16 = (wm_elems + xb_elems) * sizeof(short);   // 288 MiB
  const size_t need_split = need_bf16 + out_elems * sizeof(float);  // 320 MiB

  if (ws_size >= need_split) {
    short* wmb = (short*)d_ws;
    short* xbb = wmb + wm_elems;
    float* p1 = (float*)((char*)d_ws + need_bf16);
    hipLaunchKernelGGL(prep_w_kernel, dim3(4096), dim3(256), 0, stream,
                       (const f32x4*)w, (const f32x4*)mask, (u16x8*)wmb,
                       (int)(wm_elems / 8));
    hipLaunchKernelGGL(prep_x_kernel, dim3(512), dim3(256), 0, stream,
                       (const f32x4*)x, (u16x8*)xbb, (int)(xb_elems / 8));
    hipLaunchKernelGGL(gemm256, dim3(KSPLIT * MT256 * NT256), dim3(512), 0,
                       stream, xbb, wmb, out, p1);
    hipLaunchKernelGGL(reduce_kernel, dim3(2048), dim3(256), 0, stream,
                       (const f32x4*)out, (const f32x4*)p1,
                       (const f32x4*)bias, (f32x4*)out, (int)(out_elems / 4));
  } else {
    hipLaunchKernelGGL(gemm128_fused, dim3(512), dim3(256), 0, stream, x, w,
                       mask, bias, out);
  }
}

// Round 8
// 580.988 us; speedup vs baseline: 1.0338x; 1.0338x over previous
//
#include <hip/hip_runtime.h>

// out[B=1024, O=8192] = x[B, I=16384] @ (W*mask)[O, I]^T + bias[O]
// Phase 1: W*mask -> bf16 (ws), x -> bf16 (ws), nontemporal streaming.
// Phase 2: 256x256 bf16 MFMA GEMM, split-K=2, grid 256 (1 block/CU).
//          2 barriers/K-tile; B-fragments register-pipelined across tiles;
//          one unpinned {16 aF ds_read + 64 MFMA} region per tile (compiler
//          fine-grained lgkmcnt interleave); counted vmcnt(4); XOR-swizzled
//          LDS (0 conflicts, verified r5-r7). No setprio / sched_barrier.
// Phase 3: reduce partials + bias.

#define IN_DIM 16384
#define OUT_DIM 8192
#define BATCH 1024

#define BM 256
#define BN 256
#define BK 64
#define KSPLIT 2
#define K_HALF (IN_DIM / KSPLIT)  // 8192
#define NT_K (K_HALF / BK)        // 128
#define NT256 (OUT_DIM / BN)      // 32
#define MT256 (BATCH / BM)        // 4

typedef __attribute__((ext_vector_type(8))) short bf16x8;
typedef __attribute__((ext_vector_type(4))) float f32x4;
typedef __attribute__((ext_vector_type(8))) unsigned short u16x8;

__device__ __forceinline__ unsigned short f2bf(float f) {
  unsigned int u = __float_as_uint(f);
  return (unsigned short)((u + 0x7fffu + ((u >> 16) & 1u)) >> 16);
}

#define GL16(g, l)                                                \
  __builtin_amdgcn_global_load_lds(                               \
      (const __attribute__((address_space(1))) void*)(g),         \
      (__attribute__((address_space(3))) void*)(l), 16, 0, 0)

__global__ __launch_bounds__(256) void prep_w_kernel(
    const f32x4* __restrict__ w, const f32x4* __restrict__ m,
    u16x8* __restrict__ out, int n8) {
  int i = blockIdx.x * blockDim.x + threadIdx.x;
  int stride = gridDim.x * blockDim.x;
  for (; i < n8; i += stride) {
    f32x4 w0 = __builtin_nontemporal_load(&w[2 * i]);
    f32x4 w1 = __builtin_nontemporal_load(&w[2 * i + 1]);
    f32x4 m0 = __builtin_nontemporal_load(&m[2 * i]);
    f32x4 m1 = __builtin_nontemporal_load(&m[2 * i + 1]);
    u16x8 o;
    o[0] = f2bf(w0[0] * m0[0]);
    o[1] = f2bf(w0[1] * m0[1]);
    o[2] = f2bf(w0[2] * m0[2]);
    o[3] = f2bf(w0[3] * m0[3]);
    o[4] = f2bf(w1[0] * m1[0]);
    o[5] = f2bf(w1[1] * m1[1]);
    o[6] = f2bf(w1[2] * m1[2]);
    o[7] = f2bf(w1[3] * m1[3]);
    __builtin_nontemporal_store(o, &out[i]);
  }
}

__global__ __launch_bounds__(256) void prep_x_kernel(
    const f32x4* __restrict__ x, u16x8* __restrict__ out, int n8) {
  int i = blockIdx.x * blockDim.x + threadIdx.x;
  int stride = gridDim.x * blockDim.x;
  for (; i < n8; i += stride) {
    f32x4 v0 = __builtin_nontemporal_load(&x[2 * i]);
    f32x4 v1 = __builtin_nontemporal_load(&x[2 * i + 1]);
    u16x8 o;
    o[0] = f2bf(v0[0]);
    o[1] = f2bf(v0[1]);
    o[2] = f2bf(v0[2]);
    o[3] = f2bf(v0[3]);
    o[4] = f2bf(v1[0]);
    o[5] = f2bf(v1[1]);
    o[6] = f2bf(v1[2]);
    o[7] = f2bf(v1[3]);
    __builtin_nontemporal_store(o, &out[i]);
  }
}

__global__ __launch_bounds__(256) void reduce_kernel(
    const f32x4* __restrict__ p0, const f32x4* __restrict__ p1,
    const f32x4* __restrict__ bias4, f32x4* __restrict__ out, int n4) {
  int i = blockIdx.x * blockDim.x + threadIdx.x;
  int stride = gridDim.x * blockDim.x;
  for (; i < n4; i += stride) {
    f32x4 a = p0[i];
    f32x4 b = p1[i];
    f32x4 c = bias4[i & (OUT_DIM / 4 - 1)];
    out[i] = a + b + c;
  }
}

// 256x256 tile, 8 waves (2M x 4N), per-wave 128x64, split-K=2.
// bid = (mt*2+kh)*32 + nt -> all sharers of N-panel nt on one XCD.
// LDS [slot][256][64] shorts per matrix, 2 slots (128 KiB total).
// Per-tile ledger (slot s = t&1, o = s^1):
//   top:  STAGE_A(t+1 -> o)   [A(o) last read tile t-1, drained+barrier'd]
//         STAGE_B(t+2 -> s)   [B(s) reads (bF(t)) drained at t-1 tail]
//   body: 8x {2 aF ds_read; 8 MFMA}  -- ONE unpinned region, bF in regs
//   tail: vmcnt(4)  [FIFO: retires B(t+1),A(t+1); leaves B(t+2) in flight]
//         read bF(t+1) from slot o; lgkmcnt(0); s_barrier
__global__ __launch_bounds__(512, 2) void gemm256(
    const short* __restrict__ Ab, const short* __restrict__ Bb,
    float* __restrict__ out0, float* __restrict__ out1) {
  __shared__ short As[2][256 * 64];  // 2 x 32 KB
  __shared__ short Bs[2][256 * 64];  // 2 x 32 KB

  const int tid = threadIdx.x;
  const int lane = tid & 63;
  const int wv = tid >> 6;  // 0..7
  const int wr = wv >> 2;   // 0..1
  const int wc = wv & 3;    // 0..3
  const int fr = lane & 15;
  const int fq = lane >> 4;  // 0..3

  const int bid = blockIdx.x;
  const int nt = bid & (NT256 - 1);
  const int rest = bid >> 5;  // mt*2 + kh
  const int mt = rest >> 1;
  const int kh = rest & 1;
  const int row0 = mt * BM;
  const int col0 = nt * BN;
  const int kbase = kh * K_HALF;
  float* __restrict__ dst = kh ? out1 : out0;

  // Staging: per GL16 issue, 512 threads cover 64 rows x 64 cols (8 KB).
  // thread -> row tid>>3, 16B chunk (tid&7); source chunk XOR-swizzled by
  // row&7 so LDS dest stays linear (rule 21).
  const int swz8 = ((tid & 7) ^ ((tid >> 3) & 7)) * 8;  // elements
  const short* srcA = Ab + (size_t)(row0 + (tid >> 3)) * IN_DIM + kbase + swz8;
  const short* srcB = Bb + (size_t)(col0 + (tid >> 3)) * IN_DIM + kbase + swz8;
  char* ldsA = (char*)As;
  char* ldsB = (char*)Bs;
  const int stg = wv * 1024;  // wave-uniform LDS offset within an issue

#define STAGE_A(kt, s)                                                     \
  do {                                                                     \
    _Pragma("unroll") for (int i_ = 0; i_ < 4; ++i_)                       \
        GL16(srcA + (size_t)(i_ * 64) * IN_DIM + (size_t)(kt)*BK,          \
             ldsA + (s)*32768 + i_ * 8192 + stg);                          \
  } while (0)
#define STAGE_B(kt, s)                                                     \
  do {                                                                     \
    _Pragma("unroll") for (int i_ = 0; i_ < 4; ++i_)                       \
        GL16(srcB + (size_t)(i_ * 64) * IN_DIM + (size_t)(kt)*BK,          \
             ldsB + (s)*32768 + i_ * 8192 + stg);                          \
  } while (0)

  // ds_read: frag at tile row R, kchunk cg=ks*4+fq:
  // byte = slot*32768 + R*128 + ((cg ^ (R&7))*16); R&7 == fr&7 for all frags.
  const int swzslot = (fq ^ (fr & 7)) * 16;
  const int Abase = (wr * 128 + fr) * 128 + swzslot;
  const int Bbase = (wc * 64 + fr) * 128 + swzslot;

  f32x4 acc[8][4];
#pragma unroll
  for (int i = 0; i < 8; ++i)
#pragma unroll
    for (int j = 0; j < 4; ++j) acc[i][j] = (f32x4)0.f;

  bf16x8 bFv[4][2];  // B fragments of the CURRENT tile, register-pipelined

#define TILE_BODY(T, S, O, DO_SA, DO_SB, VMN, DO_BF)                       \
  do {                                                                     \
    if (DO_SA) STAGE_A((T) + 1, O);                                        \
    if (DO_SB) STAGE_B((T) + 2, S);                                        \
    const char* tA_ = (const char*)As + (S)*32768;                         \
    _Pragma("unroll") for (int m_ = 0; m_ < 8; ++m_) {                     \
      bf16x8 a0_ = *(const bf16x8*)(tA_ + (Abase + m_ * 2048));            \
      bf16x8 a1_ = *(const bf16x8*)(tA_ + ((Abase + m_ * 2048) ^ 64));     \
      _Pragma("unroll") for (int n_ = 0; n_ < 4; ++n_) {                   \
        acc[m_][n_] = __builtin_amdgcn_mfma_f32_16x16x32_bf16(             \
            a0_, bFv[n_][0], acc[m_][n_], 0, 0, 0);                        \
        acc[m_][n_] = __builtin_amdgcn_mfma_f32_16x16x32_bf16(             \
            a1_, bFv[n_][1], acc[m_][n_], 0, 0, 0);                        \
      }                                                                    \
    }                                                                      \
    asm volatile("s_waitcnt vmcnt(" #VMN ")" ::: "memory");                \
    if (DO_BF) {                                                           \
      const char* nB_ = (const char*)Bs + (O)*32768;                       \
      _Pragma("unroll") for (int n_ = 0; n_ < 4; ++n_) {                   \
        bFv[n_][0] = *(const bf16x8*)(nB_ + (Bbase + n_ * 2048));          \
        bFv[n_][1] = *(const bf16x8*)(nB_ + ((Bbase + n_ * 2048) ^ 64));   \
      }                                                                    \
      asm volatile("s_waitcnt lgkmcnt(0)" ::: "memory");                   \
    }                                                                      \
    __builtin_amdgcn_s_barrier();                                          \
  } while (0)

  // Prologue: A(0),B(0)->slot0, B(1)->slot1. vmcnt(4): certifies tile 0,
  // leaves B(1) in flight. Then bF(0) into regs.
  STAGE_A(0, 0);
  STAGE_B(0, 0);
  STAGE_B(1, 1);
  asm volatile("s_waitcnt vmcnt(4)" ::: "memory");
  __builtin_amdgcn_s_barrier();
  {
    const char* nB_ = (const char*)Bs;  // slot 0
#pragma unroll
    for (int n_ = 0; n_ < 4; ++n_) {
      bFv[n_][0] = *(const bf16x8*)(nB_ + (Bbase + n_ * 2048));
      bFv[n_][1] = *(const bf16x8*)(nB_ + ((Bbase + n_ * 2048) ^ 64));
    }
  }
  asm volatile("s_waitcnt lgkmcnt(0)" ::: "memory");
  __builtin_amdgcn_s_barrier();

  for (int tt = 0; tt < NT_K - 2; tt += 2) {
    TILE_BODY(tt, 0, 1, true, true, 4, true);
    TILE_BODY(tt + 1, 1, 0, true, true, 4, true);
  }
  // Tile 126: stage A(127) only; drain; bF(127).
  TILE_BODY(NT_K - 2, 0, 1, true, false, 0, true);
  // Tile 127: pure compute.
  TILE_BODY(NT_K - 1, 1, 0, false, false, 0, false);

  // C/D layout: col = lane&15, row = (lane>>4)*4 + reg
#pragma unroll
  for (int m = 0; m < 8; ++m) {
#pragma unroll
    for (int n = 0; n < 4; ++n) {
      const int c = col0 + wc * 64 + n * 16 + fr;
      const int rb = row0 + wr * 128 + m * 16 + fq * 4;
#pragma unroll
      for (int tt = 0; tt < 4; ++tt)
        dst[(size_t)(rb + tt) * OUT_DIM + c] = acc[m][n][tt];
    }
  }
#undef TILE_BODY
#undef STAGE_A
#undef STAGE_B
}

// Fallback (ws too small): fused f32->bf16 128x128 kernel, verified round 1.
__global__ __launch_bounds__(256) void gemm128_fused(
    const float* __restrict__ X, const float* __restrict__ W,
    const float* __restrict__ Msk, const float* __restrict__ bias,
    float* __restrict__ out) {
  __shared__ short As[128 * BK];
  __shared__ short Bs[128 * BK];
  const int tid = threadIdx.x;
  const int lane = tid & 63;
  const int wv4 = tid >> 6;
  const int wm = wv4 >> 1;
  const int wn = wv4 & 1;
  const int fr = lane & 15;
  const int fq = lane >> 4;
  const int bid = blockIdx.x;
  const int nt = bid & 63;
  const int mt = bid >> 6;
  const int row0 = mt * 128;
  const int col0 = nt * 128;
  f32x4 acc[4][4];
#pragma unroll
  for (int i = 0; i < 4; ++i)
#pragma unroll
    for (int j = 0; j < 4; ++j) acc[i][j] = (f32x4)0.f;
  for (int kt = 0; kt < IN_DIM / BK; ++kt) {
    const int k0 = kt * BK;
    __syncthreads();
#pragma unroll
    for (int is = 0; is < 4; ++is) {
      const int e = (is * 256 + tid) * 8;
      const int r = e >> 6;
      const int kk = e & 63;
      {
        const float* src = X + (size_t)(row0 + r) * IN_DIM + k0 + kk;
        f32x4 a0 = *(const f32x4*)src;
        f32x4 a1 = *(const f32x4*)(src + 4);
        bf16x8 v;
        v[0] = (short)f2bf(a0[0]); v[1] = (short)f2bf(a0[1]);
        v[2] = (short)f2bf(a0[2]); v[3] = (short)f2bf(a0[3]);
        v[4] = (short)f2bf(a1[0]); v[5] = (short)f2bf(a1[1]);
        v[6] = (short)f2bf(a1[2]); v[7] = (short)f2bf(a1[3]);
        *(bf16x8*)&As[r * BK + kk] = v;
      }
      {
        const float* sw = W + (size_t)(col0 + r) * IN_DIM + k0 + kk;
        const float* sm = Msk + (size_t)(col0 + r) * IN_DIM + k0 + kk;
        f32x4 w0 = *(const f32x4*)sw;
        f32x4 w1 = *(const f32x4*)(sw + 4);
        f32x4 m0 = *(const f32x4*)sm;
        f32x4 m1 = *(const f32x4*)(sm + 4);
        bf16x8 v;
        v[0] = (short)f2bf(w0[0] * m0[0]); v[1] = (short)f2bf(w0[1] * m0[1]);
        v[2] = (short)f2bf(w0[2] * m0[2]); v[3] = (short)f2bf(w0[3] * m0[3]);
        v[4] = (short)f2bf(w1[0] * m1[0]); v[5] = (short)f2bf(w1[1] * m1[1]);
        v[6] = (short)f2bf(w1[2] * m1[2]); v[7] = (short)f2bf(w1[3] * m1[3]);
        *(bf16x8*)&Bs[r * BK + kk] = v;
      }
    }
    __syncthreads();
#pragma unroll
    for (int ks = 0; ks < 2; ++ks) {
      bf16x8 af[4], bf[4];
#pragma unroll
      for (int i = 0; i < 4; ++i)
        af[i] = *(const bf16x8*)&As[(wm * 64 + i * 16 + fr) * BK + ks * 32 + fq * 8];
#pragma unroll
      for (int j = 0; j < 4; ++j)
        bf[j] = *(const bf16x8*)&Bs[(wn * 64 + j * 16 + fr) * BK + ks * 32 + fq * 8];
#pragma unroll
      for (int i = 0; i < 4; ++i)
#pragma unroll
        for (int j = 0; j < 4; ++j)
          acc[i][j] = __builtin_amdgcn_mfma_f32_16x16x32_bf16(af[i], bf[j],
                                                              acc[i][j], 0, 0, 0);
    }
  }
#pragma unroll
  for (int j = 0; j < 4; ++j) {
    const int c = col0 + wn * 64 + j * 16 + fr;
    const float bv = bias[c];
#pragma unroll
    for (int i = 0; i < 4; ++i) {
      const int rb = row0 + wm * 64 + i * 16 + fq * 4;
#pragma unroll
      for (int tt = 0; tt < 4; ++tt)
        out[(size_t)(rb + tt) * OUT_DIM + c] = acc[i][j][tt] + bv;
    }
  }
}

extern "C" void kernel_launch(void* const* d_in, const int* in_sizes, int n_in,
                              void* d_out, int out_size, void* d_ws, size_t ws_size,
                              hipStream_t stream) {
  const float* x = (const float*)d_in[0];
  const float* w = (const float*)d_in[1];
  const float* bias = (const float*)d_in[2];
  const float* mask = (const float*)d_in[3];
  float* out = (float*)d_out;

  const size_t wm_elems = (size_t)OUT_DIM * IN_DIM;
  const size_t xb_elems = (size_t)BATCH * IN_DIM;
  const size_t out_elems = (size_t)BATCH * OUT_DIM;
  const size_t need_bf16 = (wm_elems + xb_elems) * sizeof(short);   // 288 MiB
  const size_t need_split = need_bf16 + out_elems * sizeof(float);  // 320 MiB

  if (ws_size >= need_split) {
    short* wmb = (short*)d_ws;
    short* xbb = wmb + wm_elems;
    float* p1 = (float*)((char*)d_ws + need_bf16);
    hipLaunchKernelGGL(prep_w_kernel, dim3(4096), dim3(256), 0, stream,
                       (const f32x4*)w, (const f32x4*)mask, (u16x8*)wmb,
                       (int)(wm_elems / 8));
    hipLaunchKernelGGL(prep_x_kernel, dim3(512), dim3(256), 0, stream,
                       (const f32x4*)x, (u16x8*)xbb, (int)(xb_elems / 8));
    hipLaunchKernelGGL(gemm256, dim3(KSPLIT * MT256 * NT256), dim3(512), 0,
                       stream, xbb, wmb, out, p1);
    hipLaunchKernelGGL(reduce_kernel, dim3(2048), dim3(256), 0, stream,
                       (const f32x4*)out, (const f32x4*)p1,
                       (const f32x4*)bias, (f32x4*)out, (int)(out_elems / 4));
  } else {
    hipLaunchKernelGGL(gemm128_fused, dim3(512), dim3(256), 0, stream, x, w,
                       mask, bias, out);
  }
}

// Round 11
// 550.970 us; speedup vs baseline: 1.0902x; 1.0545x over previous
//
#include <hip/hip_runtime.h>

// out[B=1024, O=8192] = x[B, I=16384] @ (W*mask)[O, I]^T + bias[O]
// Phase 1: W*mask -> bf16 (ws), x -> bf16 (ws), nontemporal streaming.
// Phase 2: 256x256 bf16 MFMA GEMM, split-K=2, grid 256 (1 block/CU),
//          16 waves/block (4x4 wave grid, 64x64 per wave, acc=64 regs ->
//          4 waves/SIMD), 2 barriers/tile, single-type counted vmcnt(4),
//          XOR-swizzled LDS (0 conflicts, verified r5-r8).
// Phase 3: reduce partials + bias.

#define IN_DIM 16384
#define OUT_DIM 8192
#define BATCH 1024

#define BM 256
#define BN 256
#define BK 64
#define KSPLIT 2
#define K_HALF (IN_DIM / KSPLIT)  // 8192
#define NT_K (K_HALF / BK)        // 128
#define NT256 (OUT_DIM / BN)      // 32
#define MT256 (BATCH / BM)        // 4

typedef __attribute__((ext_vector_type(8))) short bf16x8;
typedef __attribute__((ext_vector_type(4))) float f32x4;
typedef __attribute__((ext_vector_type(8))) unsigned short u16x8;

__device__ __forceinline__ unsigned short f2bf(float f) {
  unsigned int u = __float_as_uint(f);
  return (unsigned short)((u + 0x7fffu + ((u >> 16) & 1u)) >> 16);
}

#define GL16(g, l)                                                \
  __builtin_amdgcn_global_load_lds(                               \
      (const __attribute__((address_space(1))) void*)(g),         \
      (__attribute__((address_space(3))) void*)(l), 16, 0, 0)

__global__ __launch_bounds__(256) void prep_w_kernel(
    const f32x4* __restrict__ w, const f32x4* __restrict__ m,
    u16x8* __restrict__ out, int n8) {
  int i = blockIdx.x * blockDim.x + threadIdx.x;
  int stride = gridDim.x * blockDim.x;
  for (; i < n8; i += stride) {
    f32x4 w0 = __builtin_nontemporal_load(&w[2 * i]);
    f32x4 w1 = __builtin_nontemporal_load(&w[2 * i + 1]);
    f32x4 m0 = __builtin_nontemporal_load(&m[2 * i]);
    f32x4 m1 = __builtin_nontemporal_load(&m[2 * i + 1]);
    u16x8 o;
    o[0] = f2bf(w0[0] * m0[0]);
    o[1] = f2bf(w0[1] * m0[1]);
    o[2] = f2bf(w0[2] * m0[2]);
    o[3] = f2bf(w0[3] * m0[3]);
    o[4] = f2bf(w1[0] * m1[0]);
    o[5] = f2bf(w1[1] * m1[1]);
    o[6] = f2bf(w1[2] * m1[2]);
    o[7] = f2bf(w1[3] * m1[3]);
    __builtin_nontemporal_store(o, &out[i]);
  }
}

__global__ __launch_bounds__(256) void prep_x_kernel(
    const f32x4* __restrict__ x, u16x8* __restrict__ out, int n8) {
  int i = blockIdx.x * blockDim.x + threadIdx.x;
  int stride = gridDim.x * blockDim.x;
  for (; i < n8; i += stride) {
    f32x4 v0 = __builtin_nontemporal_load(&x[2 * i]);
    f32x4 v1 = __builtin_nontemporal_load(&x[2 * i + 1]);
    u16x8 o;
    o[0] = f2bf(v0[0]);
    o[1] = f2bf(v0[1]);
    o[2] = f2bf(v0[2]);
    o[3] = f2bf(v0[3]);
    o[4] = f2bf(v1[0]);
    o[5] = f2bf(v1[1]);
    o[6] = f2bf(v1[2]);
    o[7] = f2bf(v1[3]);
    __builtin_nontemporal_store(o, &out[i]);
  }
}

__global__ __launch_bounds__(256) void reduce_kernel(
    const f32x4* __restrict__ p0, const f32x4* __restrict__ p1,
    const f32x4* __restrict__ bias4, f32x4* __restrict__ out, int n4) {
  int i = blockIdx.x * blockDim.x + threadIdx.x;
  int stride = gridDim.x * blockDim.x;
  for (; i < n4; i += stride) {
    f32x4 a = p0[i];
    f32x4 b = p1[i];
    f32x4 c = bias4[i & (OUT_DIM / 4 - 1)];
    out[i] = a + b + c;
  }
}

// 256x256 tile, 16 waves (4M x 4N), per-wave 64x64, split-K=2.
// bid = (mt*2+kh)*32 + nt -> all sharers of N-panel nt on one XCD.
// LDS [slot][256][64] shorts per matrix (2 slots, 128 KiB total).
// Per tile t (slot s=t&1, o=s^1):
//   STAGE A,B(t+1)->o (4 GL16/wave); vmcnt(4) [single-type FIFO: retires
//   tile t's 4, leaves t+1's 4 in flight]; barrier; compute slot s
//   (compiler-scheduled ds_read/MFMA interleave, no pinning); barrier.
__global__ __launch_bounds__(1024, 4) void gemm256(
    const short* __restrict__ Ab, const short* __restrict__ Bb,
    float* __restrict__ out0, float* __restrict__ out1) {
  __shared__ short As[2][256 * 64];  // 2 x 32 KB
  __shared__ short Bs[2][256 * 64];  // 2 x 32 KB

  const int tid = threadIdx.x;
  const int lane = tid & 63;
  const int wv = tid >> 6;   // 0..15
  const int wr = wv >> 2;    // 0..3
  const int wc = wv & 3;     // 0..3
  const int fr = lane & 15;
  const int fq = lane >> 4;  // 0..3

  const int bid = blockIdx.x;
  const int nt = bid & (NT256 - 1);
  const int rest = bid >> 5;  // mt*2 + kh
  const int mt = rest >> 1;
  const int kh = rest & 1;
  const int row0 = mt * BM;
  const int col0 = nt * BN;
  const int kbase = kh * K_HALF;
  float* __restrict__ dst = kh ? out1 : out0;

  // Staging: per GL16 issue, 1024 threads cover 128 rows x 64 cols (16 KB).
  // thread -> row tid>>3, 16B chunk (tid&7); source chunk XOR-swizzled by
  // row&7 (rule 21: linear LDS dest, swizzled source + swizzled read).
  const int swz8 = ((tid & 7) ^ ((tid >> 3) & 7)) * 8;  // elements
  const short* srcA = Ab + (size_t)(row0 + (tid >> 3)) * IN_DIM + kbase + swz8;
  const short* srcB = Bb + (size_t)(col0 + (tid >> 3)) * IN_DIM + kbase + swz8;
  char* ldsA = (char*)As;
  char* ldsB = (char*)Bs;
  const int stg = wv * 1024;  // wave-uniform slice within a 16 KB issue

#define STAGE_A(KT, SL)                                                    \
  do {                                                                     \
    GL16(srcA + (size_t)(KT)*64, ldsA + (SL)*32768 + stg);                 \
    GL16(srcA + (size_t)128 * IN_DIM + (size_t)(KT)*64,                    \
         ldsA + (SL)*32768 + 16384 + stg);                                 \
  } while (0)
#define STAGE_B(KT, SL)                                                    \
  do {                                                                     \
    GL16(srcB + (size_t)(KT)*64, ldsB + (SL)*32768 + stg);                 \
    GL16(srcB + (size_t)128 * IN_DIM + (size_t)(KT)*64,                    \
         ldsB + (SL)*32768 + 16384 + stg);                                 \
  } while (0)

  // ds_read: frag at tile row R, kchunk cg=ks*4+fq lives at byte
  //   slot*32768 + R*128 + ((cg ^ (R&7))*16);  R&7 == fr&7 for all frags.
  const int swzslot = (fq ^ (fr & 7)) * 16;
  const int Abase = (wr * 64 + fr) * 128 + swzslot;
  const int Bbase = (wc * 64 + fr) * 128 + swzslot;

  f32x4 acc[4][4];
#pragma unroll
  for (int i = 0; i < 4; ++i)
#pragma unroll
    for (int j = 0; j < 4; ++j) acc[i][j] = (f32x4)0.f;

  // Prologue: tile 0 -> slot 0.
  STAGE_A(0, 0);
  STAGE_B(0, 0);

#pragma unroll 1
  for (int t = 0; t < NT_K; ++t) {
    const int cur = t & 1;
    if (t + 1 < NT_K) {
      STAGE_A(t + 1, cur ^ 1);
      STAGE_B(t + 1, cur ^ 1);
      // Single-type FIFO: 8 outstanding (4 of tile t late + 4 of t+1);
      // vmcnt(4) certifies all of tile t, leaves t+1 in flight.
      asm volatile("s_waitcnt vmcnt(4)" ::: "memory");
    } else {
      asm volatile("s_waitcnt vmcnt(0)" ::: "memory");
    }
    __builtin_amdgcn_s_barrier();  // tile t resident for all waves

    const char* tA = (const char*)As + cur * 32768;
    const char* tB = (const char*)Bs + cur * 32768;
#pragma unroll
    for (int ks = 0; ks < 2; ++ks) {
      const int off = ks << 6;
      bf16x8 bF[4];
#pragma unroll
      for (int n = 0; n < 4; ++n)
        bF[n] = *(const bf16x8*)(tB + ((Bbase + n * 2048) ^ off));
#pragma unroll
      for (int m = 0; m < 4; ++m) {
        bf16x8 aF = *(const bf16x8*)(tA + ((Abase + m * 2048) ^ off));
#pragma unroll
        for (int n = 0; n < 4; ++n)
          acc[m][n] = __builtin_amdgcn_mfma_f32_16x16x32_bf16(aF, bF[n],
                                                              acc[m][n], 0, 0,
                                                              0);
      }
    }
    __builtin_amdgcn_s_barrier();  // all reads of slot cur done -> next
                                   // iteration may overwrite it
  }

  // C/D layout: col = lane&15, row = (lane>>4)*4 + reg
#pragma unroll
  for (int m = 0; m < 4; ++m) {
#pragma unroll
    for (int n = 0; n < 4; ++n) {
      const int c = col0 + wc * 64 + n * 16 + fr;
      const int rb = row0 + wr * 64 + m * 16 + fq * 4;
#pragma unroll
      for (int tt = 0; tt < 4; ++tt)
        dst[(size_t)(rb + tt) * OUT_DIM + c] = acc[m][n][tt];
    }
  }
#undef STAGE_A
#undef STAGE_B
}

// Fallback (ws too small): fused f32->bf16 128x128 kernel, verified round 1.
__global__ __launch_bounds__(256) void gemm128_fused(
    const float* __restrict__ X, const float* __restrict__ W,
    const float* __restrict__ Msk, const float* __restrict__ bias,
    float* __restrict__ out) {
  __shared__ short As[128 * 64];
  __shared__ short Bs[128 * 64];
  const int tid = threadIdx.x;
  const int lane = tid & 63;
  const int wv4 = tid >> 6;
  const int wm = wv4 >> 1;
  const int wn = wv4 & 1;
  const int fr = lane & 15;
  const int fq = lane >> 4;
  const int bid = blockIdx.x;
  const int nt = bid & 63;
  const int mt = bid >> 6;
  const int row0 = mt * 128;
  const int col0 = nt * 128;
  f32x4 acc[4][4];
#pragma unroll
  for (int i = 0; i < 4; ++i)
#pragma unroll
    for (int j = 0; j < 4; ++j) acc[i][j] = (f32x4)0.f;
  for (int kt = 0; kt < IN_DIM / 64; ++kt) {
    const int k0 = kt * 64;
    __syncthreads();
#pragma unroll
    for (int is = 0; is < 4; ++is) {
      const int e = (is * 256 + tid) * 8;
      const int r = e >> 6;
      const int kk = e & 63;
      {
        const float* src = X + (size_t)(row0 + r) * IN_DIM + k0 + kk;
        f32x4 a0 = *(const f32x4*)src;
        f32x4 a1 = *(const f32x4*)(src + 4);
        bf16x8 v;
        v[0] = (short)f2bf(a0[0]); v[1] = (short)f2bf(a0[1]);
        v[2] = (short)f2bf(a0[2]); v[3] = (short)f2bf(a0[3]);
        v[4] = (short)f2bf(a1[0]); v[5] = (short)f2bf(a1[1]);
        v[6] = (short)f2bf(a1[2]); v[7] = (short)f2bf(a1[3]);
        *(bf16x8*)&As[r * 64 + kk] = v;
      }
      {
        const float* sw = W + (size_t)(col0 + r) * IN_DIM + k0 + kk;
        const float* sm = Msk + (size_t)(col0 + r) * IN_DIM + k0 + kk;
        f32x4 w0 = *(const f32x4*)sw;
        f32x4 w1 = *(const f32x4*)(sw + 4);
        f32x4 m0 = *(const f32x4*)sm;
        f32x4 m1 = *(const f32x4*)(sm + 4);
        bf16x8 v;
        v[0] = (short)f2bf(w0[0] * m0[0]); v[1] = (short)f2bf(w0[1] * m0[1]);
        v[2] = (short)f2bf(w0[2] * m0[2]); v[3] = (short)f2bf(w0[3] * m0[3]);
        v[4] = (short)f2bf(w1[0] * m1[0]); v[5] = (short)f2bf(w1[1] * m1[1]);
        v[6] = (short)f2bf(w1[2] * m1[2]); v[7] = (short)f2bf(w1[3] * m1[3]);
        *(bf16x8*)&Bs[r * 64 + kk] = v;
      }
    }
    __syncthreads();
#pragma unroll
    for (int ks = 0; ks < 2; ++ks) {
      bf16x8 af[4], bf[4];
#pragma unroll
      for (int i = 0; i < 4; ++i)
        af[i] = *(const bf16x8*)&As[(wm * 64 + i * 16 + fr) * 64 + ks * 32 + fq * 8];
#pragma unroll
      for (int j = 0; j < 4; ++j)
        bf[j] = *(const bf16x8*)&Bs[(wn * 64 + j * 16 + fr) * 64 + ks * 32 + fq * 8];
#pragma unroll
      for (int i = 0; i < 4; ++i)
#pragma unroll
        for (int j = 0; j < 4; ++j)
          acc[i][j] = __builtin_amdgcn_mfma_f32_16x16x32_bf16(af[i], bf[j],
                                                              acc[i][j], 0, 0, 0);
    }
  }
#pragma unroll
  for (int j = 0; j < 4; ++j) {
    const int c = col0 + wn * 64 + j * 16 + fr;
    const float bv = bias[c];
#pragma unroll
    for (int i = 0; i < 4; ++i) {
      const int rb = row0 + wm * 64 + i * 16 + fq * 4;
#pragma unroll
      for (int tt = 0; tt < 4; ++tt)
        out[(size_t)(rb + tt) * OUT_DIM + c] = acc[i][j][tt] + bv;
    }
  }
}

extern "C" void kernel_launch(void* const* d_in, const int* in_sizes, int n_in,
                              void* d_out, int out_size, void* d_ws, size_t ws_size,
                              hipStream_t stream) {
  const float* x = (const float*)d_in[0];
  const float* w = (const float*)d_in[1];
  const float* bias = (const float*)d_in[2];
  const float* mask = (const float*)d_in[3];
  float* out = (float*)d_out;

  const size_t wm_elems = (size_t)OUT_DIM * IN_DIM;
  const size_t xb_elems = (size_t)BATCH * IN_DIM;
  const size_t out_elems = (size_t)BATCH * OUT_DIM;
  const size_t need_bf16 = (wm_elems + xb_elems) * sizeof(short);   // 288 MiB
  const size_t need_split = need_bf16 + out_elems * sizeof(float);  // 320 MiB

  if (ws_size >= need_split) {
    short* wmb = (short*)d_ws;
    short* xbb = wmb + wm_elems;
    float* p1 = (float*)((char*)d_ws + need_bf16);
    hipLaunchKernelGGL(prep_w_kernel, dim3(4096), dim3(256), 0, stream,
                       (const f32x4*)w, (const f32x4*)mask, (u16x8*)wmb,
                       (int)(wm_elems / 8));
    hipLaunchKernelGGL(prep_x_kernel, dim3(512), dim3(256), 0, stream,
                       (const f32x4*)x, (u16x8*)xbb, (int)(xb_elems / 8));
    hipLaunchKernelGGL(gemm256, dim3(KSPLIT * MT256 * NT256), dim3(1024), 0,
                       stream, xbb, wmb, out, p1);
    hipLaunchKernelGGL(reduce_kernel, dim3(2048), dim3(256), 0, stream,
                       (const f32x4*)out, (const f32x4*)p1,
                       (const f32x4*)bias, (f32x4*)out, (int)(out_elems / 4));
  } else {
    hipLaunchKernelGGL(gemm128_fused, dim3(512), dim3(256), 0, stream, x, w,
                       mask, bias, out);
  }
}